// Round 1
// baseline (247.537 us; speedup 1.0000x reference)
//
#include <hip/hip_runtime.h>
#include <hip/hip_bf16.h>
#include <math.h>
#include <stdint.h>

#define NROWS 1000000
#define NCOLS 100
#define NBINS 20
#define W     50000u
#define NBUCK 260096   // 0x3F800000 >> 12  (conf in [0,1))
#define CHUNK 4096
#define NCHUNK 64      // ceil(NBUCK/CHUNK)
#define SUBN  4096     // 2^12 fine buckets (low 12 bits)
#define NB    19       // number of bin boundaries
#define LDSN  8192     // LDS-cached hot buckets (top of range)

// ---------- ws layout (bytes) ----------
#define OFF_HIST    0u
#define OFF_SUBHIST 1040384u            // 260096*4
#define OFF_BINS    1351680u            // +19*4096*4 ; 8-aligned
#define ZERO_BYTES  1352000u            // hist+subhist+bins zeroed each launch
#define OFF_PREFIX  1352000u
#define OFF_CHUNKS  2392384u            // +260096*4
#define OFF_BND     2392640u            // +64*4
#define OFF_SUBPREF 2392768u            // padded
#define OFF_CONF    2704064u            // +19*4096*4
#define OFF_ACC     6704064u            // +1000000*4

// ---------- K1: per-row max/argmax, thread per row, float4 loads ----------
__global__ __launch_bounds__(256) void k1_rowmax(const float* __restrict__ x,
                                                 const int* __restrict__ labels,
                                                 float* __restrict__ conf,
                                                 unsigned char* __restrict__ acc) {
    int row = blockIdx.x * blockDim.x + threadIdx.x;
    if (row >= NROWS) return;
    const float4* r4 = reinterpret_cast<const float4*>(x + (size_t)row * NCOLS);
    float best = -1.0f;
    int bi = 0;
    #pragma unroll
    for (int k = 0; k < 25; k++) {
        float4 v = r4[k];
        if (v.x > best) { best = v.x; bi = 4 * k + 0; }
        if (v.y > best) { best = v.y; bi = 4 * k + 1; }
        if (v.z > best) { best = v.z; bi = 4 * k + 2; }
        if (v.w > best) { best = v.w; bi = 4 * k + 3; }
    }
    conf[row] = best;
    acc[row] = (bi == labels[row]) ? 1 : 0;
}

// ---------- K2: coarse histogram (bits>>12), LDS cache for hot top range ----------
__global__ __launch_bounds__(256) void k2_hist(const float* __restrict__ conf,
                                               unsigned int* __restrict__ hist) {
    __shared__ unsigned int lh[LDSN];
    for (int i = threadIdx.x; i < LDSN; i += blockDim.x) lh[i] = 0u;
    __syncthreads();
    const unsigned int base = NBUCK - LDSN;
    int stride = gridDim.x * blockDim.x;
    for (int i = blockIdx.x * blockDim.x + threadIdx.x; i < NROWS; i += stride) {
        unsigned int b = __float_as_uint(conf[i]) >> 12;
        if (b >= NBUCK) b = NBUCK - 1;
        if (b >= base) atomicAdd(&lh[b - base], 1u);
        else           atomicAdd(&hist[b], 1u);
    }
    __syncthreads();
    for (int i = threadIdx.x; i < LDSN; i += blockDim.x) {
        unsigned int c = lh[i];
        if (c) atomicAdd(&hist[base + i], c);
    }
}

// ---------- K3a: per-chunk local exclusive scan + chunk totals ----------
__global__ __launch_bounds__(256) void k3_scan1(const unsigned int* __restrict__ hist,
                                                unsigned int* __restrict__ prefix,
                                                unsigned int* __restrict__ chunks) {
    __shared__ unsigned int s[256];
    int tid = threadIdx.x;
    int base = blockIdx.x * CHUNK + tid * 16;
    unsigned int loc[16];
    unsigned int tot = 0;
    #pragma unroll
    for (int k = 0; k < 16; k++) {
        int idx = base + k;
        unsigned int v = (idx < NBUCK) ? hist[idx] : 0u;
        loc[k] = tot; tot += v;
    }
    s[tid] = tot; __syncthreads();
    for (int off = 1; off < 256; off <<= 1) {
        unsigned int v = (tid >= off) ? s[tid - off] : 0u;
        __syncthreads();
        s[tid] += v;
        __syncthreads();
    }
    unsigned int excl = s[tid] - tot;
    #pragma unroll
    for (int k = 0; k < 16; k++) {
        int idx = base + k;
        if (idx < NBUCK) prefix[idx] = excl + loc[k];
    }
    if (tid == 255) chunks[blockIdx.x] = s[255];
}

// ---------- K3b: exclusive scan of 64 chunk totals (one wave) ----------
__global__ __launch_bounds__(64) void k3_scan2(unsigned int* __restrict__ chunks) {
    int lane = threadIdx.x;
    int v = (int)chunks[lane];
    int orig = v;
    for (int off = 1; off < 64; off <<= 1) {
        int n = __shfl_up(v, off);
        if (lane >= off) v += n;
    }
    chunks[lane] = (unsigned int)(v - orig);
}

// ---------- K3c: add chunk offsets ----------
__global__ __launch_bounds__(256) void k3_scan3(unsigned int* __restrict__ prefix,
                                                const unsigned int* __restrict__ chunks) {
    unsigned int add = chunks[blockIdx.x];
    #pragma unroll
    for (int k = 0; k < 16; k++) {
        int idx = blockIdx.x * CHUNK + threadIdx.x + k * 256;
        if (idx < NBUCK) prefix[idx] += add;
    }
}

// ---------- K4: locate split (boundary) buckets via binary search ----------
__global__ __launch_bounds__(64) void k4_bounds(const unsigned int* __restrict__ prefix,
                                                unsigned int* __restrict__ bnd) {
    int t = threadIdx.x;
    if (t >= NB) return;
    unsigned int r = (unsigned int)(t + 1) * W;
    int lo = 0, hi = NBUCK - 1;
    while (lo < hi) {
        int mid = (lo + hi + 1) >> 1;
        if (prefix[mid] <= r) lo = mid; else hi = mid - 1;
    }
    bnd[t] = (prefix[lo] < r) ? (unsigned int)lo : 0xFFFFFFFFu;
}

// ---------- K5: fine 12-bit sub-histogram for boundary buckets ----------
__global__ __launch_bounds__(256) void k5_subhist(const float* __restrict__ conf,
                                                  const unsigned int* __restrict__ bnd,
                                                  unsigned int* __restrict__ subhist) {
    __shared__ unsigned int sb[NB];
    if (threadIdx.x < NB) sb[threadIdx.x] = bnd[threadIdx.x];
    __syncthreads();
    int stride = gridDim.x * blockDim.x;
    for (int i = blockIdx.x * blockDim.x + threadIdx.x; i < NROWS; i += stride) {
        unsigned int bits = __float_as_uint(conf[i]);
        unsigned int t = bits >> 12; if (t >= NBUCK) t = NBUCK - 1;
        int s = -1;
        #pragma unroll
        for (int k = 0; k < NB; k++) { if (sb[k] == t) { s = k; break; } }
        if (s >= 0) atomicAdd(&subhist[s * SUBN + (bits & 0xFFFu)], 1u);
    }
}

// ---------- K6: exclusive scan of each 4096-entry sub-histogram ----------
__global__ __launch_bounds__(256) void k6_subscan(const unsigned int* __restrict__ subhist,
                                                  unsigned int* __restrict__ subpref) {
    __shared__ unsigned int s[256];
    int slot = blockIdx.x;
    int tid = threadIdx.x;
    const unsigned int* in = subhist + slot * SUBN;
    unsigned int* out = subpref + slot * SUBN;
    unsigned int loc[16];
    unsigned int tot = 0;
    int base = tid * 16;
    #pragma unroll
    for (int k = 0; k < 16; k++) { loc[k] = tot; tot += in[base + k]; }
    s[tid] = tot; __syncthreads();
    for (int off = 1; off < 256; off <<= 1) {
        unsigned int v = (tid >= off) ? s[tid - off] : 0u;
        __syncthreads();
        s[tid] += v;
        __syncthreads();
    }
    unsigned int excl = s[tid] - tot;
    #pragma unroll
    for (int k = 0; k < 16; k++) out[base + k] = excl + loc[k];
}

// ---------- K7: per-bin accumulation (LDS f32 bins -> global f64 bins) ----------
__global__ __launch_bounds__(256) void k7_accum(const float* __restrict__ conf,
                                                const unsigned char* __restrict__ acc,
                                                const unsigned int* __restrict__ prefix,
                                                const unsigned int* __restrict__ hist,
                                                const unsigned int* __restrict__ bnd,
                                                const unsigned int* __restrict__ subhist,
                                                const unsigned int* __restrict__ subpref,
                                                double* __restrict__ bins) {
    __shared__ float sc[NBINS], sa[NBINS];
    __shared__ unsigned int sb[NB];
    if (threadIdx.x < NBINS) { sc[threadIdx.x] = 0.f; sa[threadIdx.x] = 0.f; }
    if (threadIdx.x < NB) sb[threadIdx.x] = bnd[threadIdx.x];
    __syncthreads();
    int stride = gridDim.x * blockDim.x;
    for (int i = blockIdx.x * blockDim.x + threadIdx.x; i < NROWS; i += stride) {
        float c = conf[i];
        float a = (float)acc[i];
        unsigned int bits = __float_as_uint(c);
        unsigned int t = bits >> 12; if (t >= NBUCK) t = NBUCK - 1;
        unsigned int p = prefix[t], cnt = hist[t];
        unsigned int b0 = p / W, b1 = (p + cnt - 1) / W;
        if (b0 == b1) {
            atomicAdd(&sc[b0], c); atomicAdd(&sa[b0], a);
        } else {
            int s = -1;
            #pragma unroll
            for (int k = 0; k < NB; k++) { if (sb[k] == t) { s = k; break; } }
            if (s < 0) { // shouldn't happen; safe fallback
                atomicAdd(&sc[b0], c); atomicAdd(&sa[b0], a);
            } else {
                unsigned int f  = bits & 0xFFFu;
                unsigned int r0 = p + subpref[s * SUBN + f];
                unsigned int m  = subhist[s * SUBN + f];
                unsigned int bb0 = r0 / W, bb1 = (r0 + m - 1) / W;
                if (bb0 == bb1) {
                    atomicAdd(&sc[bb0], c); atomicAdd(&sa[bb0], a);
                } else { // exact-tie run straddles a boundary: fractional split
                    unsigned int low = (bb0 + 1) * W - r0;
                    float fr = (float)low / (float)m;
                    atomicAdd(&sc[bb0], c * fr);          atomicAdd(&sa[bb0], a * fr);
                    atomicAdd(&sc[bb1], c * (1.f - fr));  atomicAdd(&sa[bb1], a * (1.f - fr));
                }
            }
        }
    }
    __syncthreads();
    if (threadIdx.x < NBINS) {
        atomicAdd(&bins[threadIdx.x],          (double)sc[threadIdx.x]);
        atomicAdd(&bins[NBINS + threadIdx.x],  (double)sa[threadIdx.x]);
    }
}

// ---------- K8: finalize ----------
__global__ __launch_bounds__(64) void k8_final(const double* __restrict__ bins,
                                               float* __restrict__ out) {
    if (threadIdx.x == 0) {
        double ece = 0.0;
        for (int b = 0; b < NBINS; b++) {
            double avc = bins[b] / (double)W;
            double ava = bins[NBINS + b] / (double)W;
            ece += fabs(avc - ava);
            out[1 + b] = (float)ava;
        }
        out[0] = (float)(ece * ((double)W / (double)NROWS));
    }
}

extern "C" void kernel_launch(void* const* d_in, const int* in_sizes, int n_in,
                              void* d_out, int out_size, void* d_ws, size_t ws_size,
                              hipStream_t stream) {
    const float* x      = (const float*)d_in[0];
    const int*   labels = (const int*)d_in[1];
    float*       out    = (float*)d_out;
    char*        ws     = (char*)d_ws;

    unsigned int*  hist    = (unsigned int*)(ws + OFF_HIST);
    unsigned int*  subhist = (unsigned int*)(ws + OFF_SUBHIST);
    double*        bins    = (double*)      (ws + OFF_BINS);
    unsigned int*  prefix  = (unsigned int*)(ws + OFF_PREFIX);
    unsigned int*  chunks  = (unsigned int*)(ws + OFF_CHUNKS);
    unsigned int*  bnd     = (unsigned int*)(ws + OFF_BND);
    unsigned int*  subpref = (unsigned int*)(ws + OFF_SUBPREF);
    float*         conf    = (float*)       (ws + OFF_CONF);
    unsigned char* acc     = (unsigned char*)(ws + OFF_ACC);

    // zero hist + subhist + bins (accumulated into every call)
    hipMemsetAsync(ws, 0, ZERO_BYTES, stream);

    k1_rowmax<<<(NROWS + 255) / 256, 256, 0, stream>>>(x, labels, conf, acc);
    k2_hist  <<<1024, 256, 0, stream>>>(conf, hist);
    k3_scan1 <<<NCHUNK, 256, 0, stream>>>(hist, prefix, chunks);
    k3_scan2 <<<1, 64, 0, stream>>>(chunks);
    k3_scan3 <<<NCHUNK, 256, 0, stream>>>(prefix, chunks);
    k4_bounds<<<1, 64, 0, stream>>>(prefix, bnd);
    k5_subhist<<<1024, 256, 0, stream>>>(conf, bnd, subhist);
    k6_subscan<<<NB, 256, 0, stream>>>(subhist, subpref);
    k7_accum <<<2048, 256, 0, stream>>>(conf, acc, prefix, hist, bnd, subhist, subpref, bins);
    k8_final <<<1, 64, 0, stream>>>(bins, out);
}

// Round 2
// 245.356 us; speedup vs baseline: 1.0089x; 1.0089x over previous
//
#include <hip/hip_runtime.h>
#include <hip/hip_bf16.h>
#include <math.h>
#include <stdint.h>

#define NROWS 1000000
#define NCOLS 100
#define NBINS 20
#define W     50000u
#define NBUCK 260096   // 0x3F800000 >> 12  (conf in [0,1))
#define CHUNK 4096
#define NCHUNK 64      // ceil(NBUCK/CHUNK)
#define SUBN  4096     // 2^12 fine buckets (low 12 bits)
#define NB    19       // number of bin boundaries
#define LDSN  8192     // LDS-cached hot buckets (top of range)

// ---------- ws layout (bytes) ----------
#define OFF_HIST    0u
#define OFF_SUBHIST 1040384u            // 260096*4
#define OFF_BINS    1351680u            // +19*4096*4 ; 8-aligned
#define ZERO_BYTES  1352000u            // hist+subhist+bins, zeroed inside k1
#define ZERO_DW     338000u             // ZERO_BYTES/4
#define OFF_PREFIX  1352000u
#define OFF_CHUNKS  2392384u            // +260096*4
#define OFF_BND     2392640u            // +64*4
#define OFF_SUBPREF 2392768u            // padded
#define OFF_CONF    2704064u            // +19*4096*4
#define OFF_ACC     6704064u            // +1000000*4

// ---------- K1: per-row max/argmax + inline zeroing of hist/subhist/bins ----
__global__ __launch_bounds__(256) void k1_rowmax(const float* __restrict__ x,
                                                 const int* __restrict__ labels,
                                                 float* __restrict__ conf,
                                                 unsigned char* __restrict__ acc,
                                                 unsigned int* __restrict__ zero_region) {
    int row = blockIdx.x * blockDim.x + threadIdx.x;
    // zero the hist+subhist+bins region (consumed by later kernels; stream
    // ordering makes this safe — no other kernel runs concurrently with k1)
    if (row < ZERO_DW) zero_region[row] = 0u;
    if (row >= NROWS) return;
    const float4* r4 = reinterpret_cast<const float4*>(x + (size_t)row * NCOLS);
    float best = -1.0f;
    int bi = 0;
    #pragma unroll
    for (int k = 0; k < 25; k++) {
        float4 v = r4[k];
        if (v.x > best) { best = v.x; bi = 4 * k + 0; }
        if (v.y > best) { best = v.y; bi = 4 * k + 1; }
        if (v.z > best) { best = v.z; bi = 4 * k + 2; }
        if (v.w > best) { best = v.w; bi = 4 * k + 3; }
    }
    conf[row] = best;
    acc[row] = (bi == labels[row]) ? 1 : 0;
}

// ---------- K2: coarse histogram (bits>>12), LDS cache for hot top range ----
__global__ __launch_bounds__(256) void k2_hist(const float* __restrict__ conf,
                                               unsigned int* __restrict__ hist) {
    __shared__ unsigned int lh[LDSN];
    for (int i = threadIdx.x; i < LDSN; i += blockDim.x) lh[i] = 0u;
    __syncthreads();
    const unsigned int base = NBUCK - LDSN;
    int stride = gridDim.x * blockDim.x;
    for (int i = blockIdx.x * blockDim.x + threadIdx.x; i < NROWS; i += stride) {
        unsigned int b = __float_as_uint(conf[i]) >> 12;
        if (b >= NBUCK) b = NBUCK - 1;
        if (b >= base) atomicAdd(&lh[b - base], 1u);
        else           atomicAdd(&hist[b], 1u);
    }
    __syncthreads();
    for (int i = threadIdx.x; i < LDSN; i += blockDim.x) {
        unsigned int c = lh[i];
        if (c) atomicAdd(&hist[base + i], c);
    }
}

// ---------- K3a: per-chunk local exclusive scan + chunk totals ----------
__global__ __launch_bounds__(256) void k3_scan1(const unsigned int* __restrict__ hist,
                                                unsigned int* __restrict__ prefix,
                                                unsigned int* __restrict__ chunks) {
    __shared__ unsigned int s[256];
    int tid = threadIdx.x;
    int base = blockIdx.x * CHUNK + tid * 16;
    unsigned int loc[16];
    unsigned int tot = 0;
    #pragma unroll
    for (int k = 0; k < 16; k++) {
        int idx = base + k;
        unsigned int v = (idx < NBUCK) ? hist[idx] : 0u;
        loc[k] = tot; tot += v;
    }
    s[tid] = tot; __syncthreads();
    for (int off = 1; off < 256; off <<= 1) {
        unsigned int v = (tid >= off) ? s[tid - off] : 0u;
        __syncthreads();
        s[tid] += v;
        __syncthreads();
    }
    unsigned int excl = s[tid] - tot;
    #pragma unroll
    for (int k = 0; k < 16; k++) {
        int idx = base + k;
        if (idx < NBUCK) prefix[idx] = excl + loc[k];
    }
    if (tid == 255) chunks[blockIdx.x] = s[255];
}

// ---------- K3b: exclusive scan of 64 chunk totals (one wave) ----------
__global__ __launch_bounds__(64) void k3_scan2(unsigned int* __restrict__ chunks) {
    int lane = threadIdx.x;
    int v = (int)chunks[lane];
    int orig = v;
    for (int off = 1; off < 64; off <<= 1) {
        int n = __shfl_up(v, off);
        if (lane >= off) v += n;
    }
    chunks[lane] = (unsigned int)(v - orig);
}

// ---------- K3c: add chunk offsets ----------
__global__ __launch_bounds__(256) void k3_scan3(unsigned int* __restrict__ prefix,
                                                const unsigned int* __restrict__ chunks) {
    unsigned int add = chunks[blockIdx.x];
    #pragma unroll
    for (int k = 0; k < 16; k++) {
        int idx = blockIdx.x * CHUNK + threadIdx.x + k * 256;
        if (idx < NBUCK) prefix[idx] += add;
    }
}

// ---------- K4: locate split (boundary) buckets via binary search ----------
__global__ __launch_bounds__(64) void k4_bounds(const unsigned int* __restrict__ prefix,
                                                unsigned int* __restrict__ bnd) {
    int t = threadIdx.x;
    if (t >= NB) return;
    unsigned int r = (unsigned int)(t + 1) * W;
    int lo = 0, hi = NBUCK - 1;
    while (lo < hi) {
        int mid = (lo + hi + 1) >> 1;
        if (prefix[mid] <= r) lo = mid; else hi = mid - 1;
    }
    bnd[t] = (prefix[lo] < r) ? (unsigned int)lo : 0xFFFFFFFFu;
}

// ---------- K5: fine 12-bit sub-histogram for boundary buckets ----------
__global__ __launch_bounds__(256) void k5_subhist(const float* __restrict__ conf,
                                                  const unsigned int* __restrict__ bnd,
                                                  unsigned int* __restrict__ subhist) {
    __shared__ unsigned int sb[NB];
    if (threadIdx.x < NB) sb[threadIdx.x] = bnd[threadIdx.x];
    __syncthreads();
    int stride = gridDim.x * blockDim.x;
    for (int i = blockIdx.x * blockDim.x + threadIdx.x; i < NROWS; i += stride) {
        unsigned int bits = __float_as_uint(conf[i]);
        unsigned int t = bits >> 12; if (t >= NBUCK) t = NBUCK - 1;
        int s = -1;
        #pragma unroll
        for (int k = 0; k < NB; k++) { if (sb[k] == t) { s = k; break; } }
        if (s >= 0) atomicAdd(&subhist[s * SUBN + (bits & 0xFFFu)], 1u);
    }
}

// ---------- K6: exclusive scan of each 4096-entry sub-histogram ----------
__global__ __launch_bounds__(256) void k6_subscan(const unsigned int* __restrict__ subhist,
                                                  unsigned int* __restrict__ subpref) {
    __shared__ unsigned int s[256];
    int slot = blockIdx.x;
    int tid = threadIdx.x;
    const unsigned int* in = subhist + slot * SUBN;
    unsigned int* out = subpref + slot * SUBN;
    unsigned int loc[16];
    unsigned int tot = 0;
    int base = tid * 16;
    #pragma unroll
    for (int k = 0; k < 16; k++) { loc[k] = tot; tot += in[base + k]; }
    s[tid] = tot; __syncthreads();
    for (int off = 1; off < 256; off <<= 1) {
        unsigned int v = (tid >= off) ? s[tid - off] : 0u;
        __syncthreads();
        s[tid] += v;
        __syncthreads();
    }
    unsigned int excl = s[tid] - tot;
    #pragma unroll
    for (int k = 0; k < 16; k++) out[base + k] = excl + loc[k];
}

// ---------- K7: per-bin accumulation (per-wave LDS bins -> global f64) -----
__global__ __launch_bounds__(256) void k7_accum(const float* __restrict__ conf,
                                                const unsigned char* __restrict__ acc,
                                                const unsigned int* __restrict__ prefix,
                                                const unsigned int* __restrict__ hist,
                                                const unsigned int* __restrict__ bnd,
                                                const unsigned int* __restrict__ subhist,
                                                const unsigned int* __restrict__ subpref,
                                                double* __restrict__ bins) {
    __shared__ float sc[4][NBINS], sa[4][NBINS];   // per-wave replicas
    __shared__ unsigned int sb[NB];
    for (int i = threadIdx.x; i < 4 * NBINS; i += blockDim.x) {
        (&sc[0][0])[i] = 0.f; (&sa[0][0])[i] = 0.f;
    }
    if (threadIdx.x < NB) sb[threadIdx.x] = bnd[threadIdx.x];
    __syncthreads();
    int wid = threadIdx.x >> 6;
    int stride = gridDim.x * blockDim.x;
    for (int i = blockIdx.x * blockDim.x + threadIdx.x; i < NROWS; i += stride) {
        float c = conf[i];
        float a = (float)acc[i];
        unsigned int bits = __float_as_uint(c);
        unsigned int t = bits >> 12; if (t >= NBUCK) t = NBUCK - 1;
        unsigned int p = prefix[t], cnt = hist[t];
        unsigned int b0 = p / W, b1 = (p + cnt - 1) / W;
        if (b0 == b1) {
            atomicAdd(&sc[wid][b0], c); atomicAdd(&sa[wid][b0], a);
        } else {
            int s = -1;
            #pragma unroll
            for (int k = 0; k < NB; k++) { if (sb[k] == t) { s = k; break; } }
            if (s < 0) { // shouldn't happen; safe fallback
                atomicAdd(&sc[wid][b0], c); atomicAdd(&sa[wid][b0], a);
            } else {
                unsigned int f  = bits & 0xFFFu;
                unsigned int r0 = p + subpref[s * SUBN + f];
                unsigned int m  = subhist[s * SUBN + f];
                unsigned int bb0 = r0 / W, bb1 = (r0 + m - 1) / W;
                if (bb0 == bb1) {
                    atomicAdd(&sc[wid][bb0], c); atomicAdd(&sa[wid][bb0], a);
                } else { // exact-tie run straddles a boundary: fractional split
                    unsigned int low = (bb0 + 1) * W - r0;
                    float fr = (float)low / (float)m;
                    atomicAdd(&sc[wid][bb0], c * fr);          atomicAdd(&sa[wid][bb0], a * fr);
                    atomicAdd(&sc[wid][bb1], c * (1.f - fr));  atomicAdd(&sa[wid][bb1], a * (1.f - fr));
                }
            }
        }
    }
    __syncthreads();
    if (threadIdx.x < NBINS) {
        float tc = sc[0][threadIdx.x] + sc[1][threadIdx.x] + sc[2][threadIdx.x] + sc[3][threadIdx.x];
        float ta = sa[0][threadIdx.x] + sa[1][threadIdx.x] + sa[2][threadIdx.x] + sa[3][threadIdx.x];
        atomicAdd(&bins[threadIdx.x],          (double)tc);
        atomicAdd(&bins[NBINS + threadIdx.x],  (double)ta);
    }
}

// ---------- K8: finalize ----------
__global__ __launch_bounds__(64) void k8_final(const double* __restrict__ bins,
                                               float* __restrict__ out) {
    if (threadIdx.x == 0) {
        double ece = 0.0;
        for (int b = 0; b < NBINS; b++) {
            double avc = bins[b] / (double)W;
            double ava = bins[NBINS + b] / (double)W;
            ece += fabs(avc - ava);
            out[1 + b] = (float)ava;
        }
        out[0] = (float)(ece * ((double)W / (double)NROWS));
    }
}

extern "C" void kernel_launch(void* const* d_in, const int* in_sizes, int n_in,
                              void* d_out, int out_size, void* d_ws, size_t ws_size,
                              hipStream_t stream) {
    const float* x      = (const float*)d_in[0];
    const int*   labels = (const int*)d_in[1];
    float*       out    = (float*)d_out;
    char*        ws     = (char*)d_ws;

    unsigned int*  hist    = (unsigned int*)(ws + OFF_HIST);
    unsigned int*  subhist = (unsigned int*)(ws + OFF_SUBHIST);
    double*        bins    = (double*)      (ws + OFF_BINS);
    unsigned int*  prefix  = (unsigned int*)(ws + OFF_PREFIX);
    unsigned int*  chunks  = (unsigned int*)(ws + OFF_CHUNKS);
    unsigned int*  bnd     = (unsigned int*)(ws + OFF_BND);
    unsigned int*  subpref = (unsigned int*)(ws + OFF_SUBPREF);
    float*         conf    = (float*)       (ws + OFF_CONF);
    unsigned char* acc     = (unsigned char*)(ws + OFF_ACC);
    unsigned int*  zr      = (unsigned int*)(ws + OFF_HIST);  // contiguous zero region

    k1_rowmax<<<(NROWS + 255) / 256, 256, 0, stream>>>(x, labels, conf, acc, zr);
    k2_hist  <<<1024, 256, 0, stream>>>(conf, hist);
    k3_scan1 <<<NCHUNK, 256, 0, stream>>>(hist, prefix, chunks);
    k3_scan2 <<<1, 64, 0, stream>>>(chunks);
    k3_scan3 <<<NCHUNK, 256, 0, stream>>>(prefix, chunks);
    k4_bounds<<<1, 64, 0, stream>>>(prefix, bnd);
    k5_subhist<<<1024, 256, 0, stream>>>(conf, bnd, subhist);
    k6_subscan<<<NB, 256, 0, stream>>>(subhist, subpref);
    k7_accum <<<2048, 256, 0, stream>>>(conf, acc, prefix, hist, bnd, subhist, subpref, bins);
    k8_final <<<1, 64, 0, stream>>>(bins, out);
}

// Round 3
// 229.222 us; speedup vs baseline: 1.0799x; 1.0704x over previous
//
#include <hip/hip_runtime.h>
#include <hip/hip_bf16.h>
#include <math.h>
#include <stdint.h>

#define NROWS 1000000
#define NCOLS 100
#define NBINS 20
#define NB    19       // bin boundaries
#define W     50000u   // rows per bin
#define NH    2049     // local buckets: 0 = catch-all (<0.5), 1..2048 = [0.5,1) in 2^-12 steps
#define SUBN  4096     // fine buckets (low 12 mantissa bits)
#define BBASE 258048u  // 0x3F000000 >> 12

// ---------- ws layout (dword offsets) ----------
#define HIST_DW   0u        // len 2052 (NH padded)
#define SUB_DW    2052u     // len NB*SUBN = 77824
#define BINS_DW   79876u    // len 80 dwords = 40 doubles (byte 319504, 8-aligned)
#define ZERO_DW   79956u    // everything below zeroed in k1
#define PREF_DW   79960u    // len 2052
#define BND_DW    82012u    // len 20
#define BF_DW     82032u    // len 20 : fine threshold per boundary
#define BL_DW     82052u    // len 20 : low count at threshold
#define BM_DW     82072u    // len 20 : total count at threshold
#define CONF_DW   82096u    // len 1000000 (byte 328384, 16B-aligned); sign bit = accuracy

__device__ __forceinline__ unsigned int bucket_of(unsigned int bits) {
    // bits = positive-f32 pattern (sign stripped). conf < 0.5 -> 0 (catch-all).
    if (bits < 0x3F000000u) return 0u;
    unsigned int t = (bits >> 12) - BBASE + 1u;   // 1..2048 for [0.5,1)
    return t > 2048u ? 2048u : t;                 // defensive clamp (conf<1 always)
}

// ---------- K1: wave-cooperative row max/argmax; acc packed in sign bit ----
// Each 32-lane half-wave handles one row: lanes 0-24 load 25 float4 (400B
// contiguous; two halves -> 800B contiguous per wave instruction), then a
// 5-step shfl_xor max/argmax reduce (first-index tie-break).
__global__ __launch_bounds__(256) void k1_rowmax(const float* __restrict__ x,
                                                 const int* __restrict__ labels,
                                                 float* __restrict__ conf,
                                                 unsigned int* __restrict__ zero_region) {
    int gtid = blockIdx.x * blockDim.x + threadIdx.x;
    if (gtid < (int)ZERO_DW) zero_region[gtid] = 0u;   // hist+subhist+bins

    int wave = gtid >> 6;
    int lane = threadIdx.x & 63;
    int half = lane >> 5;
    int l    = lane & 31;
    int nwaves = (gridDim.x * blockDim.x) >> 6;

    for (int rp = wave; rp < NROWS / 2; rp += nwaves) {
        int row = rp * 2 + half;
        const float4* r4 = reinterpret_cast<const float4*>(x + (size_t)row * NCOLS);
        float best = -1.0f;
        int bi = 999;
        if (l < 25) {
            float4 v = r4[l];
            best = v.x; bi = 4 * l;
            if (v.y > best) { best = v.y; bi = 4 * l + 1; }
            if (v.z > best) { best = v.z; bi = 4 * l + 2; }
            if (v.w > best) { best = v.w; bi = 4 * l + 3; }
        }
        #pragma unroll
        for (int mask = 16; mask >= 1; mask >>= 1) {
            float ov = __shfl_xor(best, mask);
            int   oi = __shfl_xor(bi,   mask);
            if (ov > best || (ov == best && oi < bi)) { best = ov; bi = oi; }
        }
        if (l == 0) {
            unsigned int cb = __float_as_uint(best);
            if (bi == labels[row]) cb |= 0x80000000u;
            conf[row] = __uint_as_float(cb);
        }
    }
}

// ---------- K2: 2049-bucket histogram, per-block LDS, big blocks ----------
__global__ __launch_bounds__(512) void k2_hist(const float* __restrict__ conf,
                                               unsigned int* __restrict__ hist) {
    __shared__ unsigned int lh[NH];
    for (int i = threadIdx.x; i < NH; i += blockDim.x) lh[i] = 0u;
    __syncthreads();
    const uint4* c4 = reinterpret_cast<const uint4*>(conf);
    int stride = gridDim.x * blockDim.x;
    for (int i = blockIdx.x * blockDim.x + threadIdx.x; i < NROWS / 4; i += stride) {
        uint4 v = c4[i];
        atomicAdd(&lh[bucket_of(v.x & 0x7FFFFFFFu)], 1u);
        atomicAdd(&lh[bucket_of(v.y & 0x7FFFFFFFu)], 1u);
        atomicAdd(&lh[bucket_of(v.z & 0x7FFFFFFFu)], 1u);
        atomicAdd(&lh[bucket_of(v.w & 0x7FFFFFFFu)], 1u);
    }
    __syncthreads();
    for (int i = threadIdx.x; i < NH; i += blockDim.x) {
        unsigned int c = lh[i];
        if (c) atomicAdd(&hist[i], c);
    }
}

// ---------- K3: single-block scan of 2049 + boundary search ----------
__global__ __launch_bounds__(256) void k3_scan_bounds(const unsigned int* __restrict__ hist,
                                                      unsigned int* __restrict__ prefix,
                                                      unsigned int* __restrict__ bnd) {
    __shared__ unsigned int s[256];
    __shared__ unsigned int sp[NH];
    int tid = threadIdx.x;
    unsigned int loc[9];
    unsigned int tot = 0;
    int base = tid * 9;
    #pragma unroll
    for (int k = 0; k < 9; k++) {
        int idx = base + k;
        unsigned int v = (idx < NH) ? hist[idx] : 0u;
        loc[k] = tot; tot += v;
    }
    s[tid] = tot; __syncthreads();
    for (int off = 1; off < 256; off <<= 1) {
        unsigned int v = (tid >= off) ? s[tid - off] : 0u;
        __syncthreads();
        s[tid] += v;
        __syncthreads();
    }
    unsigned int excl = s[tid] - tot;
    #pragma unroll
    for (int k = 0; k < 9; k++) {
        int idx = base + k;
        if (idx < NH) { unsigned int e = excl + loc[k]; prefix[idx] = e; sp[idx] = e; }
    }
    __syncthreads();
    if (tid < NB) {
        unsigned int r = (unsigned int)(tid + 1) * W;
        int lo = 0, hi = NH - 1;
        while (lo < hi) {
            int mid = (lo + hi + 1) >> 1;
            if (sp[mid] <= r) lo = mid; else hi = mid - 1;
        }
        bnd[tid] = (sp[lo] < r) ? (unsigned int)lo : 0xFFFFFFFFu;
    }
}

// ---------- K5: fine sub-histogram for boundary buckets (LDS slot table) ---
__global__ __launch_bounds__(256) void k5_subhist(const float* __restrict__ conf,
                                                  const unsigned int* __restrict__ bnd,
                                                  unsigned int* __restrict__ subhist) {
    __shared__ int stab[NH];
    for (int i = threadIdx.x; i < NH; i += blockDim.x) stab[i] = -1;
    __syncthreads();
    if (threadIdx.x < NB) {
        unsigned int b = bnd[threadIdx.x];
        if (b != 0xFFFFFFFFu) stab[b] = threadIdx.x;
    }
    __syncthreads();
    const uint4* c4 = reinterpret_cast<const uint4*>(conf);
    int stride = gridDim.x * blockDim.x;
    for (int i = blockIdx.x * blockDim.x + threadIdx.x; i < NROWS / 4; i += stride) {
        uint4 v = c4[i];
        unsigned int bs[4] = { v.x, v.y, v.z, v.w };
        #pragma unroll
        for (int j = 0; j < 4; j++) {
            unsigned int bits = bs[j] & 0x7FFFFFFFu;
            int s = stab[bucket_of(bits)];
            if (s >= 0) atomicAdd(&subhist[s * SUBN + (bits & 0xFFFu)], 1u);
        }
    }
}

// ---------- K6: per-boundary scan -> exact split {F, low, m} --------------
__global__ __launch_bounds__(256) void k6_split(const unsigned int* __restrict__ subhist,
                                                const unsigned int* __restrict__ prefix,
                                                const unsigned int* __restrict__ bnd,
                                                unsigned int* __restrict__ BF,
                                                unsigned int* __restrict__ BL,
                                                unsigned int* __restrict__ BM) {
    int slot = blockIdx.x;
    unsigned int b = bnd[slot];
    if (b == 0xFFFFFFFFu) {
        if (threadIdx.x == 0) { BF[slot] = 0xFFFFFFFFu; BL[slot] = 0u; BM[slot] = 1u; }
        return;
    }
    unsigned int offset = (unsigned int)(slot + 1) * W - prefix[b];
    __shared__ unsigned int s[256];
    int tid = threadIdx.x;
    const unsigned int* in = subhist + slot * SUBN;
    unsigned int v[16], loc[16];
    unsigned int tot = 0;
    int base = tid * 16;
    #pragma unroll
    for (int k = 0; k < 16; k++) { v[k] = in[base + k]; loc[k] = tot; tot += v[k]; }
    s[tid] = tot; __syncthreads();
    for (int off = 1; off < 256; off <<= 1) {
        unsigned int t2 = (tid >= off) ? s[tid - off] : 0u;
        __syncthreads();
        s[tid] += t2;
        __syncthreads();
    }
    unsigned int excl = s[tid] - tot;
    #pragma unroll
    for (int k = 0; k < 16; k++) {
        unsigned int ex = excl + loc[k];
        if (ex < offset && offset <= ex + v[k]) {
            BF[slot] = base + k; BL[slot] = offset - ex; BM[slot] = v[k];
        }
    }
}

// ---------- K7: binning + accumulation, all lookups in LDS ----------------
__global__ __launch_bounds__(256) void k7_accum(const float* __restrict__ conf,
                                                const unsigned int* __restrict__ prefix,
                                                const unsigned int* __restrict__ bnd,
                                                const unsigned int* __restrict__ BF,
                                                const unsigned int* __restrict__ BL,
                                                const unsigned int* __restrict__ BM,
                                                double* __restrict__ bins) {
    __shared__ unsigned int ptab[NH];           // prefix | (slot+1)<<24
    __shared__ unsigned int sF[NB];
    __shared__ float sFR[NB];
    __shared__ float sc[4][NBINS], sa[4][NBINS];
    for (int i = threadIdx.x; i < NH; i += blockDim.x) ptab[i] = prefix[i];
    for (int i = threadIdx.x; i < 4 * NBINS; i += blockDim.x) {
        (&sc[0][0])[i] = 0.f; (&sa[0][0])[i] = 0.f;
    }
    __syncthreads();
    if (threadIdx.x < NB) {
        unsigned int b = bnd[threadIdx.x];
        if (b != 0xFFFFFFFFu) ptab[b] |= (unsigned int)(threadIdx.x + 1) << 24;
        sF[threadIdx.x]  = BF[threadIdx.x];
        sFR[threadIdx.x] = (float)BL[threadIdx.x] / (float)BM[threadIdx.x];
    }
    __syncthreads();
    int wid = threadIdx.x >> 6;
    const uint4* c4 = reinterpret_cast<const uint4*>(conf);
    int stride = gridDim.x * blockDim.x;
    for (int i = blockIdx.x * blockDim.x + threadIdx.x; i < NROWS / 4; i += stride) {
        uint4 q = c4[i];
        unsigned int bs[4] = { q.x, q.y, q.z, q.w };
        #pragma unroll
        for (int j = 0; j < 4; j++) {
            unsigned int raw = bs[j];
            float a = (float)(raw >> 31);
            unsigned int bits = raw & 0x7FFFFFFFu;
            float c = __uint_as_float(bits);
            unsigned int e = ptab[bucket_of(bits)];
            unsigned int s = e >> 24;
            if (s == 0u) {
                unsigned int bin = (e & 0xFFFFFFu) / W;
                atomicAdd(&sc[wid][bin], c); atomicAdd(&sa[wid][bin], a);
            } else {
                unsigned int f = bits & 0xFFFu;
                unsigned int F = sF[s - 1];
                if (f < F)      { atomicAdd(&sc[wid][s - 1], c); atomicAdd(&sa[wid][s - 1], a); }
                else if (f > F) { atomicAdd(&sc[wid][s],     c); atomicAdd(&sa[wid][s],     a); }
                else {
                    float fr = sFR[s - 1];
                    atomicAdd(&sc[wid][s - 1], c * fr);         atomicAdd(&sa[wid][s - 1], a * fr);
                    atomicAdd(&sc[wid][s],     c * (1.f - fr)); atomicAdd(&sa[wid][s],     a * (1.f - fr));
                }
            }
        }
    }
    __syncthreads();
    if (threadIdx.x < NBINS) {
        float tc = sc[0][threadIdx.x] + sc[1][threadIdx.x] + sc[2][threadIdx.x] + sc[3][threadIdx.x];
        float ta = sa[0][threadIdx.x] + sa[1][threadIdx.x] + sa[2][threadIdx.x] + sa[3][threadIdx.x];
        atomicAdd(&bins[threadIdx.x],         (double)tc);
        atomicAdd(&bins[NBINS + threadIdx.x], (double)ta);
    }
}

// ---------- K8: finalize ----------
__global__ __launch_bounds__(64) void k8_final(const double* __restrict__ bins,
                                               float* __restrict__ out) {
    if (threadIdx.x == 0) {
        double ece = 0.0;
        for (int b = 0; b < NBINS; b++) {
            double avc = bins[b] / (double)W;
            double ava = bins[NBINS + b] / (double)W;
            ece += fabs(avc - ava);
            out[1 + b] = (float)ava;
        }
        out[0] = (float)(ece * ((double)W / (double)NROWS));
    }
}

extern "C" void kernel_launch(void* const* d_in, const int* in_sizes, int n_in,
                              void* d_out, int out_size, void* d_ws, size_t ws_size,
                              hipStream_t stream) {
    const float* x      = (const float*)d_in[0];
    const int*   labels = (const int*)d_in[1];
    float*       out    = (float*)d_out;
    unsigned int* wd    = (unsigned int*)d_ws;

    unsigned int* hist    = wd + HIST_DW;
    unsigned int* subhist = wd + SUB_DW;
    double*       bins    = (double*)(wd + BINS_DW);
    unsigned int* prefix  = wd + PREF_DW;
    unsigned int* bnd     = wd + BND_DW;
    unsigned int* BF      = wd + BF_DW;
    unsigned int* BL      = wd + BL_DW;
    unsigned int* BM      = wd + BM_DW;
    float*        conf    = (float*)(wd + CONF_DW);

    k1_rowmax     <<<1024, 256, 0, stream>>>(x, labels, conf, wd);
    k2_hist       <<<128, 512, 0, stream>>>(conf, hist);
    k3_scan_bounds<<<1, 256, 0, stream>>>(hist, prefix, bnd);
    k5_subhist    <<<256, 256, 0, stream>>>(conf, bnd, subhist);
    k6_split      <<<NB, 256, 0, stream>>>(subhist, prefix, bnd, BF, BL, BM);
    k7_accum      <<<512, 256, 0, stream>>>(conf, prefix, bnd, BF, BL, BM, bins);
    k8_final      <<<1, 64, 0, stream>>>(bins, out);
}

// Round 4
// 168.165 us; speedup vs baseline: 1.4720x; 1.3631x over previous
//
#include <hip/hip_runtime.h>
#include <hip/hip_bf16.h>
#include <math.h>
#include <stdint.h>

#define NROWS 1000000
#define NCOLS 100
#define NBINS 20
#define NB    19       // bin boundaries
#define W     50000u   // rows per bin
#define NH    2049     // local buckets: 0 = catch-all (<0.5), 1..2048 = [0.5,1) in 2^-12 steps
#define SUBN  4096     // fine buckets (low 12 mantissa bits)
#define BBASE 258048u  // 0x3F000000 >> 12

// ---------- ws layout (dword offsets) ----------
#define HIST_DW   0u        // len 2052 (NH padded)
#define SUB_DW    2052u     // len NB*SUBN = 77824
#define BINS_DW   79876u    // len 80 dwords = 40 doubles (byte 319504, 8-aligned)
#define ZERO_DW   79956u    // everything below zeroed in k1
#define PREF_DW   79960u    // len 2052
#define BND_DW    82012u    // len 20
#define BF_DW     82032u    // len 20 : fine threshold per boundary
#define BL_DW     82052u    // len 20 : low count at threshold
#define BM_DW     82072u    // len 20 : total count at threshold
#define CONF_DW   82096u    // len 1000000 (byte 328384, 16B-aligned); sign bit = accuracy

__device__ __forceinline__ unsigned int bucket_of(unsigned int bits) {
    // bits = positive-f32 pattern (sign stripped). conf < 0.5 -> 0 (catch-all).
    if (bits < 0x3F000000u) return 0u;
    unsigned int t = (bits >> 12) - BBASE + 1u;   // 1..2048 for [0.5,1)
    return t > 2048u ? 2048u : t;                 // defensive clamp (conf<1 always)
}

// ---------- K1: wave-cooperative row max/argmax; acc packed in sign bit ----
// Each 32-lane half-wave handles one row: lanes 0-24 load 25 float4 (400B
// contiguous; two halves -> 800B contiguous per wave instruction), then a
// 5-step shfl_xor max/argmax reduce (first-index tie-break).
__global__ __launch_bounds__(256) void k1_rowmax(const float* __restrict__ x,
                                                 const int* __restrict__ labels,
                                                 float* __restrict__ conf,
                                                 unsigned int* __restrict__ zero_region) {
    int gtid = blockIdx.x * blockDim.x + threadIdx.x;
    if (gtid < (int)ZERO_DW) zero_region[gtid] = 0u;   // hist+subhist+bins

    int wave = gtid >> 6;
    int lane = threadIdx.x & 63;
    int half = lane >> 5;
    int l    = lane & 31;
    int nwaves = (gridDim.x * blockDim.x) >> 6;

    for (int rp = wave; rp < NROWS / 2; rp += nwaves) {
        int row = rp * 2 + half;
        const float4* r4 = reinterpret_cast<const float4*>(x + (size_t)row * NCOLS);
        float best = -1.0f;
        int bi = 999;
        if (l < 25) {
            float4 v = r4[l];
            best = v.x; bi = 4 * l;
            if (v.y > best) { best = v.y; bi = 4 * l + 1; }
            if (v.z > best) { best = v.z; bi = 4 * l + 2; }
            if (v.w > best) { best = v.w; bi = 4 * l + 3; }
        }
        #pragma unroll
        for (int mask = 16; mask >= 1; mask >>= 1) {
            float ov = __shfl_xor(best, mask);
            int   oi = __shfl_xor(bi,   mask);
            if (ov > best || (ov == best && oi < bi)) { best = ov; bi = oi; }
        }
        if (l == 0) {
            unsigned int cb = __float_as_uint(best);
            if (bi == labels[row]) cb |= 0x80000000u;
            conf[row] = __uint_as_float(cb);
        }
    }
}

// ---------- K2: 2049-bucket histogram, per-block LDS, big blocks ----------
__global__ __launch_bounds__(512) void k2_hist(const float* __restrict__ conf,
                                               unsigned int* __restrict__ hist) {
    __shared__ unsigned int lh[NH];
    for (int i = threadIdx.x; i < NH; i += blockDim.x) lh[i] = 0u;
    __syncthreads();
    const uint4* c4 = reinterpret_cast<const uint4*>(conf);
    int stride = gridDim.x * blockDim.x;
    for (int i = blockIdx.x * blockDim.x + threadIdx.x; i < NROWS / 4; i += stride) {
        uint4 v = c4[i];
        atomicAdd(&lh[bucket_of(v.x & 0x7FFFFFFFu)], 1u);
        atomicAdd(&lh[bucket_of(v.y & 0x7FFFFFFFu)], 1u);
        atomicAdd(&lh[bucket_of(v.z & 0x7FFFFFFFu)], 1u);
        atomicAdd(&lh[bucket_of(v.w & 0x7FFFFFFFu)], 1u);
    }
    __syncthreads();
    for (int i = threadIdx.x; i < NH; i += blockDim.x) {
        unsigned int c = lh[i];
        if (c) atomicAdd(&hist[i], c);
    }
}

// ---------- K3: single-block scan of 2049 + boundary search ----------
__global__ __launch_bounds__(256) void k3_scan_bounds(const unsigned int* __restrict__ hist,
                                                      unsigned int* __restrict__ prefix,
                                                      unsigned int* __restrict__ bnd) {
    __shared__ unsigned int s[256];
    __shared__ unsigned int sp[NH];
    int tid = threadIdx.x;
    unsigned int loc[9];
    unsigned int tot = 0;
    int base = tid * 9;
    #pragma unroll
    for (int k = 0; k < 9; k++) {
        int idx = base + k;
        unsigned int v = (idx < NH) ? hist[idx] : 0u;
        loc[k] = tot; tot += v;
    }
    s[tid] = tot; __syncthreads();
    for (int off = 1; off < 256; off <<= 1) {
        unsigned int v = (tid >= off) ? s[tid - off] : 0u;
        __syncthreads();
        s[tid] += v;
        __syncthreads();
    }
    unsigned int excl = s[tid] - tot;
    #pragma unroll
    for (int k = 0; k < 9; k++) {
        int idx = base + k;
        if (idx < NH) { unsigned int e = excl + loc[k]; prefix[idx] = e; sp[idx] = e; }
    }
    __syncthreads();
    if (tid < NB) {
        unsigned int r = (unsigned int)(tid + 1) * W;
        int lo = 0, hi = NH - 1;
        while (lo < hi) {
            int mid = (lo + hi + 1) >> 1;
            if (sp[mid] <= r) lo = mid; else hi = mid - 1;
        }
        bnd[tid] = (sp[lo] < r) ? (unsigned int)lo : 0xFFFFFFFFu;
    }
}

// ---------- K5: fine sub-histogram for boundary buckets (LDS slot table) ---
__global__ __launch_bounds__(256) void k5_subhist(const float* __restrict__ conf,
                                                  const unsigned int* __restrict__ bnd,
                                                  unsigned int* __restrict__ subhist) {
    __shared__ int stab[NH];
    for (int i = threadIdx.x; i < NH; i += blockDim.x) stab[i] = -1;
    __syncthreads();
    if (threadIdx.x < NB) {
        unsigned int b = bnd[threadIdx.x];
        if (b != 0xFFFFFFFFu) stab[b] = threadIdx.x;
    }
    __syncthreads();
    const uint4* c4 = reinterpret_cast<const uint4*>(conf);
    int stride = gridDim.x * blockDim.x;
    for (int i = blockIdx.x * blockDim.x + threadIdx.x; i < NROWS / 4; i += stride) {
        uint4 v = c4[i];
        unsigned int bs[4] = { v.x, v.y, v.z, v.w };
        #pragma unroll
        for (int j = 0; j < 4; j++) {
            unsigned int bits = bs[j] & 0x7FFFFFFFu;
            int s = stab[bucket_of(bits)];
            if (s >= 0) atomicAdd(&subhist[s * SUBN + (bits & 0xFFFu)], 1u);
        }
    }
}

// ---------- K6: per-boundary scan -> exact split {F, low, m} --------------
__global__ __launch_bounds__(256) void k6_split(const unsigned int* __restrict__ subhist,
                                                const unsigned int* __restrict__ prefix,
                                                const unsigned int* __restrict__ bnd,
                                                unsigned int* __restrict__ BF,
                                                unsigned int* __restrict__ BL,
                                                unsigned int* __restrict__ BM) {
    int slot = blockIdx.x;
    unsigned int b = bnd[slot];
    if (b == 0xFFFFFFFFu) {
        if (threadIdx.x == 0) { BF[slot] = 0xFFFFFFFFu; BL[slot] = 0u; BM[slot] = 1u; }
        return;
    }
    unsigned int offset = (unsigned int)(slot + 1) * W - prefix[b];
    __shared__ unsigned int s[256];
    int tid = threadIdx.x;
    const unsigned int* in = subhist + slot * SUBN;
    unsigned int v[16], loc[16];
    unsigned int tot = 0;
    int base = tid * 16;
    #pragma unroll
    for (int k = 0; k < 16; k++) { v[k] = in[base + k]; loc[k] = tot; tot += v[k]; }
    s[tid] = tot; __syncthreads();
    for (int off = 1; off < 256; off <<= 1) {
        unsigned int t2 = (tid >= off) ? s[tid - off] : 0u;
        __syncthreads();
        s[tid] += t2;
        __syncthreads();
    }
    unsigned int excl = s[tid] - tot;
    #pragma unroll
    for (int k = 0; k < 16; k++) {
        unsigned int ex = excl + loc[k];
        if (ex < offset && offset <= ex + v[k]) {
            BF[slot] = base + k; BL[slot] = offset - ex; BM[slot] = v[k];
        }
    }
}

// ---------- K7: binning + accumulation, all lookups in LDS ----------------
__global__ __launch_bounds__(256) void k7_accum(const float* __restrict__ conf,
                                                const unsigned int* __restrict__ prefix,
                                                const unsigned int* __restrict__ bnd,
                                                const unsigned int* __restrict__ BF,
                                                const unsigned int* __restrict__ BL,
                                                const unsigned int* __restrict__ BM,
                                                double* __restrict__ bins) {
    __shared__ unsigned int ptab[NH];           // prefix | (slot+1)<<24
    __shared__ unsigned int sF[NB];
    __shared__ float sFR[NB];
    __shared__ float sc[4][NBINS], sa[4][NBINS];
    for (int i = threadIdx.x; i < NH; i += blockDim.x) ptab[i] = prefix[i];
    for (int i = threadIdx.x; i < 4 * NBINS; i += blockDim.x) {
        (&sc[0][0])[i] = 0.f; (&sa[0][0])[i] = 0.f;
    }
    __syncthreads();
    if (threadIdx.x < NB) {
        unsigned int b = bnd[threadIdx.x];
        if (b != 0xFFFFFFFFu) ptab[b] |= (unsigned int)(threadIdx.x + 1) << 24;
        sF[threadIdx.x]  = BF[threadIdx.x];
        sFR[threadIdx.x] = (float)BL[threadIdx.x] / (float)BM[threadIdx.x];
    }
    __syncthreads();
    int wid = threadIdx.x >> 6;
    const uint4* c4 = reinterpret_cast<const uint4*>(conf);
    int stride = gridDim.x * blockDim.x;
    for (int i = blockIdx.x * blockDim.x + threadIdx.x; i < NROWS / 4; i += stride) {
        uint4 q = c4[i];
        unsigned int bs[4] = { q.x, q.y, q.z, q.w };
        #pragma unroll
        for (int j = 0; j < 4; j++) {
            unsigned int raw = bs[j];
            float a = (float)(raw >> 31);
            unsigned int bits = raw & 0x7FFFFFFFu;
            float c = __uint_as_float(bits);
            unsigned int e = ptab[bucket_of(bits)];
            unsigned int s = e >> 24;
            if (s == 0u) {
                unsigned int bin = (e & 0xFFFFFFu) / W;
                atomicAdd(&sc[wid][bin], c); atomicAdd(&sa[wid][bin], a);
            } else {
                unsigned int f = bits & 0xFFFu;
                unsigned int F = sF[s - 1];
                if (f < F)      { atomicAdd(&sc[wid][s - 1], c); atomicAdd(&sa[wid][s - 1], a); }
                else if (f > F) { atomicAdd(&sc[wid][s],     c); atomicAdd(&sa[wid][s],     a); }
                else {
                    float fr = sFR[s - 1];
                    atomicAdd(&sc[wid][s - 1], c * fr);         atomicAdd(&sa[wid][s - 1], a * fr);
                    atomicAdd(&sc[wid][s],     c * (1.f - fr)); atomicAdd(&sa[wid][s],     a * (1.f - fr));
                }
            }
        }
    }
    __syncthreads();
    if (threadIdx.x < NBINS) {
        float tc = sc[0][threadIdx.x] + sc[1][threadIdx.x] + sc[2][threadIdx.x] + sc[3][threadIdx.x];
        float ta = sa[0][threadIdx.x] + sa[1][threadIdx.x] + sa[2][threadIdx.x] + sa[3][threadIdx.x];
        atomicAdd(&bins[threadIdx.x],         (double)tc);
        atomicAdd(&bins[NBINS + threadIdx.x], (double)ta);
    }
}

// ---------- K8: finalize ----------
__global__ __launch_bounds__(64) void k8_final(const double* __restrict__ bins,
                                               float* __restrict__ out) {
    if (threadIdx.x == 0) {
        double ece = 0.0;
        for (int b = 0; b < NBINS; b++) {
            double avc = bins[b] / (double)W;
            double ava = bins[NBINS + b] / (double)W;
            ece += fabs(avc - ava);
            out[1 + b] = (float)ava;
        }
        out[0] = (float)(ece * ((double)W / (double)NROWS));
    }
}

extern "C" void kernel_launch(void* const* d_in, const int* in_sizes, int n_in,
                              void* d_out, int out_size, void* d_ws, size_t ws_size,
                              hipStream_t stream) {
    const float* x      = (const float*)d_in[0];
    const int*   labels = (const int*)d_in[1];
    float*       out    = (float*)d_out;
    unsigned int* wd    = (unsigned int*)d_ws;

    unsigned int* hist    = wd + HIST_DW;
    unsigned int* subhist = wd + SUB_DW;
    double*       bins    = (double*)(wd + BINS_DW);
    unsigned int* prefix  = wd + PREF_DW;
    unsigned int* bnd     = wd + BND_DW;
    unsigned int* BF      = wd + BF_DW;
    unsigned int* BL      = wd + BL_DW;
    unsigned int* BM      = wd + BM_DW;
    float*        conf    = (float*)(wd + CONF_DW);

    k1_rowmax     <<<2048, 256, 0, stream>>>(x, labels, conf, wd);   // 8192 waves, ~61 iters
    k2_hist       <<<128, 512, 0, stream>>>(conf, hist);
    k3_scan_bounds<<<1, 256, 0, stream>>>(hist, prefix, bnd);
    k5_subhist    <<<512, 256, 0, stream>>>(conf, bnd, subhist);
    k6_split      <<<NB, 256, 0, stream>>>(subhist, prefix, bnd, BF, BL, BM);
    k7_accum      <<<512, 256, 0, stream>>>(conf, prefix, bnd, BF, BL, BM, bins);
    k8_final      <<<1, 64, 0, stream>>>(bins, out);
}